// Round 2
// baseline (714.441 us; speedup 1.0000x reference)
//
#include <hip/hip_runtime.h>
#include <hip/hip_bf16.h>
#include <cstddef>

#define B_   8
#define CIN  96
#define H_   256
#define W_   256
#define CO1  48          // conv1 output channels
#define NCH  192         // final output channels (CO1*4)
#define HO   128
#define WO   128

// conv1 LDS geometry: per input row, 12 ci-chunks (8 bf16 = 16B cell) x 258 px
#define CSTR   4128      // chunk stride = 258 px * 16B
#define SLOT   49536     // 12 * CSTR
#define LDS_SZ (3 * SLOT)   // 148608 B rolling 3-row window

typedef short  v8s __attribute__((ext_vector_type(8)));   // 8 x bf16 (4 VGPRs)
typedef float  v4f __attribute__((ext_vector_type(4)));   // MFMA acc frag

static __device__ __forceinline__ unsigned short f2bf(float f) {
    __hip_bfloat16 h = __float2bfloat16(f);   // RNE
    return *(unsigned short*)&h;
}
static __device__ __forceinline__ float bf2f(unsigned short u) {
    return __uint_as_float(((unsigned int)u) << 16);
}

// ---------------------------------------------------------------------------
// prep: w_body[co][ci][kh][kw] fp32 -> wbf[tap][co][ci] bf16
// ---------------------------------------------------------------------------
__global__ void prep_weights(const float* __restrict__ wb, unsigned short* __restrict__ wbf) {
    int o = blockIdx.x * blockDim.x + threadIdx.x;      // flat over 9*48*96
    if (o >= 9 * CO1 * CIN) return;
    int ci  = o % CIN;
    int co  = (o / CIN) % CO1;
    int tap = o / (CIN * CO1);
    wbf[o] = f2bf(wb[(co * CIN + ci) * 9 + tap]);
}

// ---------------------------------------------------------------------------
// conv1_fused: reads x (fp32 NCHW) directly; per-block rolling 3-row LDS
// window (bf16, [chunk][px] 16B cells, chunk-swizzled c^=px&3 for <=2-way
// banks); 256 blocks x 8 output rows; MFMA implicit GEMM (M=48 co,
// N=256 px, K=9 taps x 96 ci); writes y_us bf16 pixel-unshuffled.
// T14 staging: issue row h+2 global loads -> compute row h -> barrier ->
// ds_write -> barrier. x fetch = 201MB * 1.25 halo; no xt round-trip.
// ---------------------------------------------------------------------------
__global__ __launch_bounds__(256) void conv1_fused(const float* __restrict__ x,
                                                   const unsigned short* __restrict__ wbf,
                                                   unsigned short* __restrict__ y_us) {
    extern __shared__ char lds[];
    const int tid  = threadIdx.x;
    const int band = blockIdx.x;            // 0..31
    const int b    = blockIdx.y;            // 0..7
    const int h0   = band * 8;

    const int lane = tid & 63;
    const int wv   = tid >> 6;
    const int l15  = lane & 15;
    const int l4   = lane >> 4;
    const int w0   = wv * 64;

    // ---- staging-side per-thread constants: thread t owns pixel w = t ----
    const float* xb = x + ((size_t)b * CIN << 16);
    const int w   = tid;                    // 0..255
    const int wp1 = w + 1;                  // LDS px coordinate (px0/px257 = halo)
    unsigned off[12];
#pragma unroll
    for (int c = 0; c < 12; ++c)
        off[c] = (unsigned)(((c ^ (wp1 & 3)) * CSTR) + wp1 * 16);

    // ---- compute-side per-lane LDS base (px = w0+l15+kw, chunk swizzle) ----
    unsigned V[3];
#pragma unroll
    for (int kw = 0; kw < 3; ++kw)
        V[kw] = (unsigned)(((l4 ^ ((l15 + kw) & 3)) * CSTR) + (w0 + l15 + kw) * 16);

    // ---- zero the px=0 / px=257 halo cells of all 3 slots (ws poisoned) ----
    if (tid < 72) {
        int s = tid / 24, rem = tid % 24;
        int c = rem % 12, px = (rem / 12) * 257;
        *(uint4*)(lds + s * SLOT + (((c ^ (px & 3)) * CSTR) + px * 16)) =
            make_uint4(0u, 0u, 0u, 0u);
    }

    unsigned s0 = 0, s1 = SLOT, s2 = 2 * SLOT;

    // ---- prologue: stage input rows h0-1, h0, h0+1 into slots 0,1,2 ----
#pragma unroll
    for (int pr = 0; pr < 3; ++pr) {
        const int r = h0 - 1 + pr;
        const bool rok = ((unsigned)r < 256u);
        const float* xr = xb + r * 256 + w;
#pragma unroll
        for (int c = 0; c < 12; ++c) {
            float f[8];
#pragma unroll
            for (int j = 0; j < 8; ++j)
                f[j] = rok ? xr[(size_t)(8 * c + j) << 16] : 0.f;
            uint4 d;
            d.x = f2bf(f[0]) | ((unsigned)f2bf(f[1]) << 16);
            d.y = f2bf(f[2]) | ((unsigned)f2bf(f[3]) << 16);
            d.z = f2bf(f[4]) | ((unsigned)f2bf(f[5]) << 16);
            d.w = f2bf(f[6]) | ((unsigned)f2bf(f[7]) << 16);
            *(uint4*)(lds + pr * SLOT + off[c]) = d;
        }
    }
    __syncthreads();

    // ---- main loop over 8 output rows ----
#pragma unroll 1
    for (int i = 0; i < 8; ++i) {
        const int h = h0 + i;
        const bool do_stage = (i < 7);

        // issue next-row loads + pack (global latency hides under MFMAs)
        unsigned pk[12][4];
        if (do_stage) {
            const int r = h + 2;                     // h0+8 == 256 at last band -> zeros
            const bool rok = ((unsigned)r < 256u);
            const float* xr = xb + r * 256 + w;
#pragma unroll
            for (int c = 0; c < 12; ++c) {
                float f[8];
#pragma unroll
                for (int j = 0; j < 8; ++j)
                    f[j] = rok ? xr[(size_t)(8 * c + j) << 16] : 0.f;
                pk[c][0] = f2bf(f[0]) | ((unsigned)f2bf(f[1]) << 16);
                pk[c][1] = f2bf(f[2]) | ((unsigned)f2bf(f[3]) << 16);
                pk[c][2] = f2bf(f[4]) | ((unsigned)f2bf(f[5]) << 16);
                pk[c][3] = f2bf(f[6]) | ((unsigned)f2bf(f[7]) << 16);
            }
        }

        v4f acc[12];
#pragma unroll
        for (int k = 0; k < 12; ++k) acc[k] = (v4f){0.f, 0.f, 0.f, 0.f};

        const unsigned sb0 = s0, sb1 = s1, sb2 = s2;
#pragma unroll
        for (int kh = 0; kh < 3; ++kh) {
            const unsigned sb = (kh == 0) ? sb0 : (kh == 1) ? sb1 : sb2;
#pragma unroll
            for (int kw = 0; kw < 3; ++kw) {
                const char* bb = lds + sb + V[kw];
                const unsigned short* at = wbf + (3 * kh + kw) * CO1 * CIN
                                               + l15 * CIN + l4 * 8;
#pragma unroll
                for (int ks = 0; ks < 3; ++ks) {
                    v8s a0 = *(const v8s*)(at +  0 * CIN + ks * 32);
                    v8s a1 = *(const v8s*)(at + 16 * CIN + ks * 32);
                    v8s a2 = *(const v8s*)(at + 32 * CIN + ks * 32);
                    v8s b0 = *(const v8s*)(bb + ks * 16512 +   0);
                    v8s b1 = *(const v8s*)(bb + ks * 16512 + 256);
                    v8s b2 = *(const v8s*)(bb + ks * 16512 + 512);
                    v8s b3 = *(const v8s*)(bb + ks * 16512 + 768);
                    acc[0]  = __builtin_amdgcn_mfma_f32_16x16x32_bf16(a0, b0, acc[0],  0, 0, 0);
                    acc[1]  = __builtin_amdgcn_mfma_f32_16x16x32_bf16(a0, b1, acc[1],  0, 0, 0);
                    acc[2]  = __builtin_amdgcn_mfma_f32_16x16x32_bf16(a0, b2, acc[2],  0, 0, 0);
                    acc[3]  = __builtin_amdgcn_mfma_f32_16x16x32_bf16(a0, b3, acc[3],  0, 0, 0);
                    acc[4]  = __builtin_amdgcn_mfma_f32_16x16x32_bf16(a1, b0, acc[4],  0, 0, 0);
                    acc[5]  = __builtin_amdgcn_mfma_f32_16x16x32_bf16(a1, b1, acc[5],  0, 0, 0);
                    acc[6]  = __builtin_amdgcn_mfma_f32_16x16x32_bf16(a1, b2, acc[6],  0, 0, 0);
                    acc[7]  = __builtin_amdgcn_mfma_f32_16x16x32_bf16(a1, b3, acc[7],  0, 0, 0);
                    acc[8]  = __builtin_amdgcn_mfma_f32_16x16x32_bf16(a2, b0, acc[8],  0, 0, 0);
                    acc[9]  = __builtin_amdgcn_mfma_f32_16x16x32_bf16(a2, b1, acc[9],  0, 0, 0);
                    acc[10] = __builtin_amdgcn_mfma_f32_16x16x32_bf16(a2, b2, acc[10], 0, 0, 0);
                    acc[11] = __builtin_amdgcn_mfma_f32_16x16x32_bf16(a2, b3, acc[11], 0, 0, 0);
                }
            }
        }

        // epilogue: y_us[b][co*4+2dy+dx][h>>1][Wp>>1] = acc
        {
            const int dy = h & 1, hp1 = h >> 1;
#pragma unroll
            for (int mf = 0; mf < 3; ++mf) {
#pragma unroll
                for (int nf = 0; nf < 4; ++nf) {
                    const int Wp = w0 + nf * 16 + l15;
                    const int dx = Wp & 1, wq = Wp >> 1;
#pragma unroll
                    for (int r = 0; r < 4; ++r) {
                        const int co = mf * 16 + l4 * 4 + r;
                        const int n  = co * 4 + dy * 2 + dx;
                        y_us[(((size_t)b * NCH + n) << 14) + (hp1 << 7) + wq] =
                            f2bf(acc[mf * 4 + nf][r]);
                    }
                }
            }
        }

        __syncthreads();            // all waves done reading slot s0 (row h-1)
        if (do_stage) {
#pragma unroll
            for (int c = 0; c < 12; ++c) {
                uint4 d;
                d.x = pk[c][0]; d.y = pk[c][1]; d.z = pk[c][2]; d.w = pk[c][3];
                *(uint4*)(lds + s0 + off[c]) = d;
            }
        }
        __syncthreads();            // row h+2 visible
        unsigned t0 = s0; s0 = s1; s1 = s2; s2 = t0;
    }
}

// ---------------------------------------------------------------------------
// conv2: grouped 3x3 over (y_us[n] bf16, mask-unshuffled[n&3]).
// Block = one (b,n) plane x 16 rows x 128 cols; y+mask tile staged in LDS
// (mask pixel-unshuffle folded in); register row-rotation -> 6 LDS reads +
// 18 fmaf per output. 12288 blocks.
// ---------------------------------------------------------------------------
#define T2H 16
__global__ __launch_bounds__(256) void conv2_kernel(
    const unsigned short* __restrict__ y_us, const float* __restrict__ mask,
    const float* __restrict__ wproj, float* __restrict__ out)
{
    __shared__ unsigned short yt[(T2H + 2) * 132];
    __shared__ float          mt[(T2H + 2) * 132];

    const int tid  = threadIdx.x;
    const int bid  = blockIdx.x;            // 0..12287
    const int band = bid & 7;
    const int bn   = bid >> 3;              // b*192 + n
    const int b    = bn / NCH;
    const int n    = bn - b * NCH;
    const int h0   = band * T2H;
    const int q    = n & 3, dy = q >> 1, dx = q & 1;

    const unsigned short* yc = y_us + ((size_t)bn << 14);
    const float*          mk = mask + ((size_t)b << 16);

    // ---- stage (T2H+2) x 130 tile of y and unshuffled mask ----
#pragma unroll
    for (int k = 0; k < 10; ++k) {
        int idx = tid + 256 * k;
        if (idx < (T2H + 2) * 132) {
            int ly = idx / 132;
            int lx = idx - ly * 132;
            int gy = h0 - 1 + ly, gx = lx - 1;
            bool ok = ((unsigned)gy < (unsigned)HO) && ((unsigned)gx < (unsigned)WO)
                      && (lx < 130);
            yt[idx] = ok ? yc[(gy << 7) + gx] : (unsigned short)0;
            mt[idx] = ok ? mk[((2 * gy + dy) << 8) + (2 * gx + dx)] : 0.f;
        }
    }
    __syncthreads();

    // ---- weights (block-uniform -> scalar) ----
    const float* wp = wproj + n * 18;
    float wy[9], wm[9];
#pragma unroll
    for (int j = 0; j < 9; ++j) { wy[j] = wp[j]; wm[j] = wp[9 + j]; }

    const int tx = tid & 127;
    const int tz = tid >> 7;                 // 0/1 -> rows [0..7] / [8..15]
    const int rbase = tz * 8;

    float y0[3], y1[3], m0[3], m1[3];
#pragma unroll
    for (int kw = 0; kw < 3; ++kw) {
        y0[kw] = bf2f(yt[(rbase + 0) * 132 + tx + kw]);
        m0[kw] = mt[(rbase + 0) * 132 + tx + kw];
        y1[kw] = bf2f(yt[(rbase + 1) * 132 + tx + kw]);
        m1[kw] = mt[(rbase + 1) * 132 + tx + kw];
    }

#pragma unroll
    for (int i = 0; i < 8; ++i) {
        float y2[3], m2[3];
#pragma unroll
        for (int kw = 0; kw < 3; ++kw) {
            y2[kw] = bf2f(yt[(rbase + i + 2) * 132 + tx + kw]);
            m2[kw] = mt[(rbase + i + 2) * 132 + tx + kw];
        }
        float acc = 0.f;
#pragma unroll
        for (int kw = 0; kw < 3; ++kw) {
            acc = fmaf(wy[0 * 3 + kw], y0[kw], acc);
            acc = fmaf(wm[0 * 3 + kw], m0[kw], acc);
        }
#pragma unroll
        for (int kw = 0; kw < 3; ++kw) {
            acc = fmaf(wy[1 * 3 + kw], y1[kw], acc);
            acc = fmaf(wm[1 * 3 + kw], m1[kw], acc);
        }
#pragma unroll
        for (int kw = 0; kw < 3; ++kw) {
            acc = fmaf(wy[2 * 3 + kw], y2[kw], acc);
            acc = fmaf(wm[2 * 3 + kw], m2[kw], acc);
        }
        const int oy = h0 + rbase + i;
        out[((size_t)bn << 14) + (oy << 7) + tx] = acc;
#pragma unroll
        for (int kw = 0; kw < 3; ++kw) {
            y0[kw] = y1[kw]; y1[kw] = y2[kw];
            m0[kw] = m1[kw]; m1[kw] = m2[kw];
        }
    }
}

// ---------------------------------------------------------------------------
extern "C" void kernel_launch(void* const* d_in, const int* in_sizes, int n_in,
                              void* d_out, int out_size, void* d_ws, size_t ws_size,
                              hipStream_t stream) {
    const float* x      = (const float*)d_in[0];   // (8,96,256,256)
    const float* mask   = (const float*)d_in[1];   // (8,1,256,256)
    const float* w_body = (const float*)d_in[2];   // (48,96,3,3)
    const float* w_proj = (const float*)d_in[3];   // (192,2,3,3)
    float* out = (float*)d_out;                    // (8,192,128,128)

    // workspace layout
    char* p = (char*)d_ws;
    unsigned short* wbf  = (unsigned short*)p;     p += (9 * CO1 * CIN * 2 + 255) & ~255ull;  // 83 KB
    unsigned short* y_us = (unsigned short*)p;     // 50.3 MB bf16

    static bool attr_done = false;
    if (!attr_done) {
        (void)hipFuncSetAttribute(reinterpret_cast<const void*>(conv1_fused),
                                  hipFuncAttributeMaxDynamicSharedMemorySize, LDS_SZ);
        attr_done = true;
    }

    {   int nel = 9 * CO1 * CIN;
        prep_weights<<<(nel + 255) / 256, 256, 0, stream>>>(w_body, wbf); }
    {   dim3 grid(32, B_);
        conv1_fused<<<grid, 256, LDS_SZ, stream>>>(x, wbf, y_us); }
    {   conv2_kernel<<<B_ * NCH * (HO / T2H), 256, 0, stream>>>(y_us, mask, w_proj, out); }
}

// Round 4
// 429.776 us; speedup vs baseline: 1.6624x; 1.6624x over previous
//
#include <hip/hip_runtime.h>
#include <hip/hip_bf16.h>
#include <cstddef>
#include <cstdint>

#define B_   8
#define CIN  96
#define H_   256
#define W_   256
#define CO1  48          // conv1 output channels
#define NCH  192         // final output channels (CO1*4)
#define HO   128
#define WO   128

// xt row image: 258 px-major cells of 12 chunks (8 bf16 = 16B), swizzled
// cell(px,c) at px*192 + ((c ^ (px&3))<<4). 49536B used, padded to 49 KiB
// so DMA = exactly 49 x (64 lanes x 16B) instructions.
#define IMG   50176                  // 49*1024
#define IMGV  (IMG / 16)             // 3136 uint4
#define LDS1  (3 * IMG)              // conv1 rolling window: 150528 B

typedef short  v8s __attribute__((ext_vector_type(8)));   // 8 x bf16 (4 VGPRs)
typedef float  v4f __attribute__((ext_vector_type(4)));   // MFMA acc frag

static __device__ __forceinline__ unsigned short f2bf(float f) {
    __hip_bfloat16 h = __float2bfloat16(f);   // RNE
    return *(unsigned short*)&h;
}
static __device__ __forceinline__ float bf2f(unsigned short u) {
    return __uint_as_float(((unsigned int)u) << 16);
}

// ---------------------------------------------------------------------------
// prep: w_body fp32 -> wbf2 fragment-major bf16.
// frag f = (tap*3 + ks)*3 + mf; within frag, lane = l4*16+l15 holds
// A[co = mf*16+l15][ci = ks*32 + l4*8 + e] at byte lane*16 + e*2.
// Each A-frag is a contiguous 1KB -> conv1 A-loads are lane-linear dwordx4.
// ---------------------------------------------------------------------------
__global__ void prep_weights(const float* __restrict__ wb, unsigned short* __restrict__ wbf2) {
    int o = blockIdx.x * blockDim.x + threadIdx.x;      // flat over 81*512
    if (o >= 81 * 512) return;
    int f = o >> 9, r = o & 511;
    int lane = r >> 3, e = r & 7;
    int l4 = lane >> 4, l15 = lane & 15;
    int mf = f % 3, ks = (f / 3) % 3, tap = f / 9;
    int co = mf * 16 + l15;
    int ci = ks * 32 + l4 * 8 + e;
    wbf2[o] = f2bf(wb[(co * CIN + ci) * 9 + tap]);
}

// ---------------------------------------------------------------------------
// transpose_x: x (8,96,256,256) fp32 NCHW -> xt row images (8, 258, IMG).
// Image index ri = input row + 1; ri 0 / 257 are zero halo rows.
// LDS-mediated: coalesced loads -> f2bf pack -> swizzled ds_write_b128 ->
// linear uint4 stream-out (perfectly coalesced global writes).
// ---------------------------------------------------------------------------
__global__ __launch_bounds__(256) void transpose_x(const float* __restrict__ x,
                                                   char* __restrict__ xt) {
    extern __shared__ char lds[];
    const int ri = blockIdx.x;          // 0..257
    const int b  = blockIdx.y;
    const int t  = threadIdx.x;

    // zero whole image (halo px0/px257 cells, halo rows, pad)
#pragma unroll
    for (int k = 0; k < 13; ++k) {
        int s = t + 256 * k;
        if (s < IMGV) ((uint4*)lds)[s] = make_uint4(0u, 0u, 0u, 0u);
    }
    __syncthreads();

    const int h = ri - 1;
    if (0 <= h && h < 256) {            // block-uniform condition
        const float* xp = x + (((size_t)b * CIN) << 16) + (h << 8) + t;
        const int px = t + 1;
        char* cbase = lds + px * 192;
        const int s = px & 3;
#pragma unroll
        for (int c = 0; c < 12; ++c) {
            float f[8];
#pragma unroll
            for (int j = 0; j < 8; ++j)
                f[j] = xp[((size_t)(8 * c + j)) << 16];
            uint4 d;
            d.x = f2bf(f[0]) | ((unsigned)f2bf(f[1]) << 16);
            d.y = f2bf(f[2]) | ((unsigned)f2bf(f[3]) << 16);
            d.z = f2bf(f[4]) | ((unsigned)f2bf(f[5]) << 16);
            d.w = f2bf(f[6]) | ((unsigned)f2bf(f[7]) << 16);
            *(uint4*)(cbase + ((c ^ s) << 4)) = d;
        }
    }
    __syncthreads();

    const uint4* sp = (const uint4*)lds;
    uint4* dp = (uint4*)(xt + ((size_t)b * 258 + ri) * IMG);
#pragma unroll
    for (int k = 0; k < 13; ++k) {
        int s = t + 256 * k;
        if (s < IMGV) dp[s] = sp[s];
    }
}

// ---------------------------------------------------------------------------
// conv1 helpers
// ---------------------------------------------------------------------------
static __device__ __forceinline__ void dma_row(char* lds_base, const char* gsrc,
                                               int wv, int lane) {
    // 49 x global_load_lds dwordx4; waves 0..2 take 13, wave 3 takes 10.
    const int k0 = wv * 13;
    const int k1 = (k0 + 13 < 49) ? (k0 + 13) : 49;
    for (int k = k0; k < k1; ++k) {
        __builtin_amdgcn_global_load_lds(
            (const __attribute__((address_space(1))) unsigned int*)(gsrc + k * 1024 + lane * 16),
            (__attribute__((address_space(3))) unsigned int*)(lds_base + k * 1024),
            16, 0, 0);
    }
}

static __device__ __forceinline__ void kh_block(const char* bb0, const char* apl,
                                                int kh, const unsigned* U, v4f* acc) {
#pragma unroll
    for (int kw = 0; kw < 3; ++kw) {
        const char* bb = bb0 + U[kw];
#pragma unroll
        for (int ks = 0; ks < 3; ++ks) {
            const int f0 = ((kh * 3 + kw) * 3 + ks) * 3;
            v8s a0 = *(const v8s*)(apl + (f0 + 0) * 1024);
            v8s a1 = *(const v8s*)(apl + (f0 + 1) * 1024);
            v8s a2 = *(const v8s*)(apl + (f0 + 2) * 1024);
            v8s b0 = *(const v8s*)(bb + ks * 64 + 0 * 3072);
            v8s b1 = *(const v8s*)(bb + ks * 64 + 1 * 3072);
            v8s b2 = *(const v8s*)(bb + ks * 64 + 2 * 3072);
            v8s b3 = *(const v8s*)(bb + ks * 64 + 3 * 3072);
            acc[0]  = __builtin_amdgcn_mfma_f32_16x16x32_bf16(a0, b0, acc[0],  0, 0, 0);
            acc[1]  = __builtin_amdgcn_mfma_f32_16x16x32_bf16(a0, b1, acc[1],  0, 0, 0);
            acc[2]  = __builtin_amdgcn_mfma_f32_16x16x32_bf16(a0, b2, acc[2],  0, 0, 0);
            acc[3]  = __builtin_amdgcn_mfma_f32_16x16x32_bf16(a0, b3, acc[3],  0, 0, 0);
            acc[4]  = __builtin_amdgcn_mfma_f32_16x16x32_bf16(a1, b0, acc[4],  0, 0, 0);
            acc[5]  = __builtin_amdgcn_mfma_f32_16x16x32_bf16(a1, b1, acc[5],  0, 0, 0);
            acc[6]  = __builtin_amdgcn_mfma_f32_16x16x32_bf16(a1, b2, acc[6],  0, 0, 0);
            acc[7]  = __builtin_amdgcn_mfma_f32_16x16x32_bf16(a1, b3, acc[7],  0, 0, 0);
            acc[8]  = __builtin_amdgcn_mfma_f32_16x16x32_bf16(a2, b0, acc[8],  0, 0, 0);
            acc[9]  = __builtin_amdgcn_mfma_f32_16x16x32_bf16(a2, b1, acc[9],  0, 0, 0);
            acc[10] = __builtin_amdgcn_mfma_f32_16x16x32_bf16(a2, b2, acc[10], 0, 0, 0);
            acc[11] = __builtin_amdgcn_mfma_f32_16x16x32_bf16(a2, b3, acc[11], 0, 0, 0);
        }
    }
}

// ---------------------------------------------------------------------------
// conv1_dma: full-width 8-row band per block (grid 32x8 = 256 = 1/CU).
// 3-slot rolling LDS window filled by global_load_lds from xt images.
// Per row: kh0,kh1 -> [vmcnt(0) drain own DMA; s_barrier] -> issue DMA(h+2)
// into freed slot -> kh2 -> epilogue. DMA flight ~1 row; one barrier/row.
// A-frags: contiguous 1KB from wbf2 (lane*16 linear). Output y_us bf16
// pixel-unshuffled (unchanged layout).
// ---------------------------------------------------------------------------
__global__ __launch_bounds__(256) void conv1_dma(const char* __restrict__ xt,
                                                 const unsigned short* __restrict__ wbf2,
                                                 unsigned short* __restrict__ y_us) {
    extern __shared__ char lds[];
    const int band = blockIdx.x;        // 0..31
    const int b    = blockIdx.y;        // 0..7
    const int h0   = band * 8;
    const int tid  = threadIdx.x;
    const int lane = tid & 63;
    const int wv   = tid >> 6;
    const int l15  = lane & 15;
    const int l4   = lane >> 4;
    const int w0   = wv * 64;

    const char* apl    = (const char*)wbf2 + lane * 16;
    const char* xrows  = xt + (size_t)b * 258 * IMG;    // image idx = input row + 1

    unsigned U[3];
#pragma unroll
    for (int kw = 0; kw < 3; ++kw) {
        int p = w0 + l15 + kw;
        U[kw] = (unsigned)(p * 192 + ((l4 ^ (p & 3)) << 4));
    }

    char* s0 = lds;
    char* s1 = lds + IMG;
    char* s2 = lds + 2 * IMG;

    // prologue: rows h0-1, h0 landed+barriered; row h0+1 left in flight
    dma_row(s0, xrows + (size_t)(h0)     * IMG, wv, lane);
    dma_row(s1, xrows + (size_t)(h0 + 1) * IMG, wv, lane);
    asm volatile("s_waitcnt vmcnt(0)" ::: "memory");
    __builtin_amdgcn_s_barrier();
    dma_row(s2, xrows + (size_t)(h0 + 2) * IMG, wv, lane);

#pragma unroll 1
    for (int i = 0; i < 8; ++i) {
        const int h = h0 + i;
        v4f acc[12];
#pragma unroll
        for (int k = 0; k < 12; ++k) acc[k] = (v4f){0.f, 0.f, 0.f, 0.f};

        kh_block(s0, apl, 0, U, acc);       // input row h-1 (old slot)
        kh_block(s1, apl, 1, U, acc);       // input row h

        asm volatile("s_waitcnt vmcnt(0)" ::: "memory");   // own DMA(h+1) done
        __builtin_amdgcn_s_barrier();                       // all waves' done; s0 free
        __builtin_amdgcn_sched_barrier(0);

        if (i < 7)
            dma_row(s0, xrows + (size_t)(h + 3) * IMG, wv, lane);  // input row h+2

        kh_block(s2, apl, 2, U, acc);       // input row h+1

        // epilogue: D row = co = mf*16 + l4*4 + r ; D col = px = w0 + nf*16 + l15
        const int dy = h & 1, hp1 = h >> 1;
#pragma unroll
        for (int mf = 0; mf < 3; ++mf) {
#pragma unroll
            for (int nf = 0; nf < 4; ++nf) {
                const int Wp = w0 + nf * 16 + l15;
                const int dx = Wp & 1, wq = Wp >> 1;
#pragma unroll
                for (int r = 0; r < 4; ++r) {
                    const int co = mf * 16 + l4 * 4 + r;
                    const int n  = co * 4 + dy * 2 + dx;
                    y_us[(((size_t)b * NCH + n) << 14) + (hp1 << 7) + wq] =
                        f2bf(acc[mf * 4 + nf][r]);
                }
            }
        }

        char* tmp = s0; s0 = s1; s1 = s2; s2 = tmp;
    }
}

// ---------------------------------------------------------------------------
// conv2: grouped 3x3 over (y_us[n] bf16, mask-unshuffled[n&3]). Unchanged
// from the round-2 version that passed on hardware.
// ---------------------------------------------------------------------------
#define T2H 16
__global__ __launch_bounds__(256) void conv2_kernel(
    const unsigned short* __restrict__ y_us, const float* __restrict__ mask,
    const float* __restrict__ wproj, float* __restrict__ out)
{
    __shared__ unsigned short yt[(T2H + 2) * 132];
    __shared__ float          mt[(T2H + 2) * 132];

    const int tid  = threadIdx.x;
    const int bid  = blockIdx.x;            // 0..12287
    const int band = bid & 7;
    const int bn   = bid >> 3;              // b*192 + n
    const int b    = bn / NCH;
    const int n    = bn - b * NCH;
    const int h0   = band * T2H;
    const int q    = n & 3, dy = q >> 1, dx = q & 1;

    const unsigned short* yc = y_us + ((size_t)bn << 14);
    const float*          mk = mask + ((size_t)b << 16);

#pragma unroll
    for (int k = 0; k < 10; ++k) {
        int idx = tid + 256 * k;
        if (idx < (T2H + 2) * 132) {
            int ly = idx / 132;
            int lx = idx - ly * 132;
            int gy = h0 - 1 + ly, gx = lx - 1;
            bool ok = ((unsigned)gy < (unsigned)HO) && ((unsigned)gx < (unsigned)WO)
                      && (lx < 130);
            yt[idx] = ok ? yc[(gy << 7) + gx] : (unsigned short)0;
            mt[idx] = ok ? mk[((2 * gy + dy) << 8) + (2 * gx + dx)] : 0.f;
        }
    }
    __syncthreads();

    const float* wp = wproj + n * 18;
    float wy[9], wm[9];
#pragma unroll
    for (int j = 0; j < 9; ++j) { wy[j] = wp[j]; wm[j] = wp[9 + j]; }

    const int tx = tid & 127;
    const int tz = tid >> 7;
    const int rbase = tz * 8;

    float y0[3], y1[3], m0[3], m1[3];
#pragma unroll
    for (int kw = 0; kw < 3; ++kw) {
        y0[kw] = bf2f(yt[(rbase + 0) * 132 + tx + kw]);
        m0[kw] = mt[(rbase + 0) * 132 + tx + kw];
        y1[kw] = bf2f(yt[(rbase + 1) * 132 + tx + kw]);
        m1[kw] = mt[(rbase + 1) * 132 + tx + kw];
    }

#pragma unroll
    for (int i = 0; i < 8; ++i) {
        float y2[3], m2[3];
#pragma unroll
        for (int kw = 0; kw < 3; ++kw) {
            y2[kw] = bf2f(yt[(rbase + i + 2) * 132 + tx + kw]);
            m2[kw] = mt[(rbase + i + 2) * 132 + tx + kw];
        }
        float acc = 0.f;
#pragma unroll
        for (int kw = 0; kw < 3; ++kw) {
            acc = fmaf(wy[0 * 3 + kw], y0[kw], acc);
            acc = fmaf(wm[0 * 3 + kw], m0[kw], acc);
        }
#pragma unroll
        for (int kw = 0; kw < 3; ++kw) {
            acc = fmaf(wy[1 * 3 + kw], y1[kw], acc);
            acc = fmaf(wm[1 * 3 + kw], m1[kw], acc);
        }
#pragma unroll
        for (int kw = 0; kw < 3; ++kw) {
            acc = fmaf(wy[2 * 3 + kw], y2[kw], acc);
            acc = fmaf(wm[2 * 3 + kw], m2[kw], acc);
        }
        const int oy = h0 + rbase + i;
        out[((size_t)bn << 14) + (oy << 7) + tx] = acc;
#pragma unroll
        for (int kw = 0; kw < 3; ++kw) {
            y0[kw] = y1[kw]; y1[kw] = y2[kw];
            m0[kw] = m1[kw]; m1[kw] = m2[kw];
        }
    }
}

// ---------------------------------------------------------------------------
extern "C" void kernel_launch(void* const* d_in, const int* in_sizes, int n_in,
                              void* d_out, int out_size, void* d_ws, size_t ws_size,
                              hipStream_t stream) {
    const float* x      = (const float*)d_in[0];   // (8,96,256,256)
    const float* mask   = (const float*)d_in[1];   // (8,1,256,256)
    const float* w_body = (const float*)d_in[2];   // (48,96,3,3)
    const float* w_proj = (const float*)d_in[3];   // (192,2,3,3)
    float* out = (float*)d_out;                    // (8,192,128,128)

    // workspace layout
    char* p = (char*)d_ws;
    unsigned short* wbf2 = (unsigned short*)p;   p += (81 * 512 * 2 + 255) & ~255ull;           // 83 KB
    char*           xt   = p;                    p += ((size_t)B_ * 258 * IMG + 255) & ~255ull; // 103.6 MB
    unsigned short* y_us = (unsigned short*)p;   // 50.3 MB bf16

    (void)hipFuncSetAttribute(reinterpret_cast<const void*>(conv1_dma),
                              hipFuncAttributeMaxDynamicSharedMemorySize, LDS1);

    {   int nel = 81 * 512;
        prep_weights<<<(nel + 255) / 256, 256, 0, stream>>>(w_body, wbf2); }
    {   dim3 grid(258, B_);
        transpose_x<<<grid, 256, IMG, stream>>>(x, xt); }
    {   dim3 grid(32, B_);
        conv1_dma<<<grid, 256, LDS1, stream>>>(xt, wbf2, y_us); }
    {   conv2_kernel<<<B_ * NCH * (HO / T2H), 256, 0, stream>>>(y_us, mask, w_proj, out); }
}